// Round 9
// baseline (208.611 us; speedup 1.0000x reference)
//
#include <hip/hip_runtime.h>

#define B_   16
#define P_   196
#define L_   80
#define DIM1 2048
#define DIM2 300
#define ATT  512

typedef __attribute__((ext_vector_type(8))) short short8x;
typedef __attribute__((ext_vector_type(8))) unsigned short ushort8x;
typedef __attribute__((ext_vector_type(4))) float f32x4;
typedef __attribute__((ext_vector_type(4))) unsigned int uint4x;
typedef __attribute__((ext_vector_type(4))) unsigned short ushort4x;

__device__ __forceinline__ unsigned short f2bf(float f) {
    unsigned v = __float_as_uint(f);
    v += 0x7fffu + ((v >> 16) & 1u);
    return (unsigned short)(v >> 16);
}

// ---------------- w_eff[a] = sum_c Wt[c] * Wh[c,a] ----------------
__global__ __launch_bounds__(256)
void weff_kernel(const float* __restrict__ Wh, const float* __restrict__ Wt,
                 float* __restrict__ w_eff) {
    __shared__ float part[4][64];
    const int tid = threadIdx.x, lane = tid & 63, quad = tid >> 6;
    const int a = blockIdx.x * 64 + lane;
    float s = 0.f;
    const int c0 = quad * 128;
    for (int c = c0; c < c0 + 128; ++c)
        s = fmaf(Wt[c], Wh[(size_t)c * ATT + a], s);
    part[quad][lane] = s;
    __syncthreads();
    if (tid < 64)
        w_eff[blockIdx.x * 64 + tid] =
            (part[0][tid] + part[1][tid]) + (part[2][tid] + part[3][tid]);
}

// ---------------- fp32 -> bf16 (RN-even), vectorized x4 ----------------
__global__ __launch_bounds__(256)
void cvt_bf16_kernel(const float* __restrict__ in, unsigned short* __restrict__ out, int n4) {
    for (int i = blockIdx.x * 256 + threadIdx.x; i < n4; i += gridDim.x * 256) {
        uint4x u = ((const uint4x*)in)[i];
        ushort4x o;
        #pragma unroll
        for (int j = 0; j < 4; ++j) {
            unsigned v = u[j];
            v += 0x7fffu + ((v >> 16) & 1u);
            o[j] = (unsigned short)(v >> 16);
        }
        ((ushort4x*)out)[i] = o;
    }
}

// ---------- generic tiled NT GEMM (fp32): C[M,N] = A[M,K] * B[N,K]^T ----------
__global__ __launch_bounds__(256)
void gemm_nt(const float* __restrict__ A, const float* __restrict__ Bm,
             float* __restrict__ C, int M, int N, int K) {
    constexpr int BK = 16;
    __shared__ float As[BK][64];
    __shared__ float Bs[BK][64];
    const int tid  = threadIdx.x;
    const int bm   = blockIdx.x * 64;
    const int bn   = blockIdx.y * 64;
    const int ty   = tid >> 4;
    const int tx   = tid & 15;
    const int lrow = tid >> 2;
    const int lc4  = (tid & 3) << 2;
    float acc[4][4] = {};
    const float* Arow = A  + (size_t)(bm + lrow) * K;
    const float* Brow = Bm + (size_t)(bn + lrow) * K;

    for (int k0 = 0; k0 < K; k0 += BK) {
        float4 av, bv;
        if (k0 + BK <= K) {
            av = *(const float4*)(Arow + k0 + lc4);
            bv = *(const float4*)(Brow + k0 + lc4);
        } else {
            float a_[4], b_[4];
            #pragma unroll
            for (int i = 0; i < 4; ++i) {
                const int k = k0 + lc4 + i;
                a_[i] = (k < K) ? Arow[k] : 0.f;
                b_[i] = (k < K) ? Brow[k] : 0.f;
            }
            av = make_float4(a_[0], a_[1], a_[2], a_[3]);
            bv = make_float4(b_[0], b_[1], b_[2], b_[3]);
        }
        __syncthreads();
        As[lc4 + 0][lrow] = av.x;  As[lc4 + 1][lrow] = av.y;
        As[lc4 + 2][lrow] = av.z;  As[lc4 + 3][lrow] = av.w;
        Bs[lc4 + 0][lrow] = bv.x;  Bs[lc4 + 1][lrow] = bv.y;
        Bs[lc4 + 2][lrow] = bv.z;  Bs[lc4 + 3][lrow] = bv.w;
        __syncthreads();
        #pragma unroll
        for (int k = 0; k < BK; ++k) {
            const float4 a4 = *(const float4*)&As[k][ty << 2];
            const float4 b4 = *(const float4*)&Bs[k][tx << 2];
            const float ae[4] = {a4.x, a4.y, a4.z, a4.w};
            const float be[4] = {b4.x, b4.y, b4.z, b4.w};
            #pragma unroll
            for (int i = 0; i < 4; ++i)
                #pragma unroll
                for (int j = 0; j < 4; ++j)
                    acc[i][j] = fmaf(ae[i], be[j], acc[i][j]);
        }
    }
    #pragma unroll
    for (int i = 0; i < 4; ++i) {
        float4 o = make_float4(acc[i][0], acc[i][1], acc[i][2], acc[i][3]);
        *(float4*)(C + (size_t)(bm + (ty << 2) + i) * N + bn + (tx << 2)) = o;
    }
}

// ---------------- bf16 MFMA GEMM: p1b[M,N] (bf16) = x1b * W1b^T ----------------
// 64x32 tile (BK=64), 4 waves along M. grid (16 bn, 49 bm): bn-fastest shares
// the A panel (L2-resident) across consecutive blocks. Both-sides XOR swizzle.
#define GM 3136
#define GN 512
#define GK 2048

__device__ __forceinline__ void gload16(const unsigned short* g, unsigned short* l) {
    __builtin_amdgcn_global_load_lds(
        (const __attribute__((address_space(1))) unsigned int*)g,
        (__attribute__((address_space(3))) unsigned int*)l, 16, 0, 0);
}

__global__ __launch_bounds__(256)
void gemm_bf16_mfma(const unsigned short* __restrict__ Ab,
                    const unsigned short* __restrict__ Bb,
                    unsigned short* __restrict__ C) {
    __shared__ unsigned short As[2][64 * 64];
    __shared__ unsigned short Bs[2][32 * 64];
    const int tid  = threadIdx.x;
    const int wid  = tid >> 6;
    const int lane = tid & 63;
    const int bm   = blockIdx.y * 64;
    const int bn   = blockIdx.x * 32;

    const int srow = lane >> 3;                       // 0..7
    const int scol = ((lane & 7) ^ srow) << 3;        // pre-swizzled source col
    const size_t arow0 = (size_t)(bm + (wid << 4) + srow) * GK;
    const size_t brow0 = (size_t)(bn + (wid << 3) + srow) * GK;

#define STAGE_TILE(buf, k0)                                                              \
    {                                                                                    \
        gload16(Ab + arow0 + (k0) + scol,                  &As[buf][((wid << 4) + 0) * 64]); \
        gload16(Ab + arow0 + (size_t)8 * GK + (k0) + scol, &As[buf][((wid << 4) + 8) * 64]); \
        gload16(Bb + brow0 + (k0) + scol,                  &Bs[buf][(wid << 3) * 64]);       \
    }

    f32x4 acc[2] = {};
    const int fr  = lane & 15;
    const int kb  = (lane >> 4) << 3;
    const int swz = (lane & 7) << 4;

    STAGE_TILE(0, 0)
    constexpr int NT = GK / 64;
    for (int kt = 0; kt < NT; ++kt) {
        __syncthreads();
        if (kt + 1 < NT) STAGE_TILE((kt + 1) & 1, (kt + 1) * 64)
        const char* pa = (const char*)&As[kt & 1][0];
        const char* pb = (const char*)&Bs[kt & 1][0];
        #pragma unroll
        for (int kk = 0; kk < 2; ++kk) {
            const int koff = ((kk * 32 + kb) * 2) ^ swz;
            short8x a = *(const short8x*)(pa + ((wid << 4) + fr) * 128 + koff);
            short8x b[2];
            #pragma unroll
            for (int n = 0; n < 2; ++n)
                b[n] = *(const short8x*)(pb + (n * 16 + fr) * 128 + koff);
            #pragma unroll
            for (int n = 0; n < 2; ++n)
                acc[n] = __builtin_amdgcn_mfma_f32_16x16x32_bf16(a, b[n], acc[n], 0, 0, 0);
        }
        __syncthreads();
    }

    const int crow = (lane >> 4) << 2;
    #pragma unroll
    for (int n = 0; n < 2; ++n)
        #pragma unroll
        for (int j = 0; j < 4; ++j)
            C[(size_t)(bm + (wid << 4) + crow + j) * GN + bn + n * 16 + fr] =
                f2bf(acc[n][j]);
#undef STAGE_TILE
}

// ------- fused score + softmax: one block per (b,l); writes alpha -------
// p1 is bf16. 16-lane row-groups (4 rows/wave-pass), double-buffered loads,
// pair-rcp: w1*sig1+w2*sig2 = (w1*e2+w2*e1+w1+w2)/((1+e1)(1+e2)).
#define LOG2E2 2.8853900817779268f   // 2*log2(e)

__global__ __launch_bounds__(256)
void score_softmax_kernel(const unsigned short* __restrict__ p1,
                          const float* __restrict__ p2,
                          const float* __restrict__ w_eff,
                          float* __restrict__ alpha) {
    // XCD-chunked swizzle: 1280 blocks = 8 XCDs x 160 -> same-b blocks share L2
    const int bidx = blockIdx.x;
    const int bl = (bidx & 7) * 160 + (bidx >> 3);
    const int b  = bl / L_;
    __shared__ float s_t[P_];
    __shared__ float s_red[4];
    const int tid = threadIdx.x, wave = tid >> 6, lane = tid & 63;
    const int g = lane >> 4, c = lane & 15;   // row-group, lane-in-group

    // lane c handles elements 128j + 8c + e (j=0..3, e=0..7): one ushort8/j.
    const float4* gp2 = (const float4*)(p2 + (size_t)bl * ATT);
    const float4* gw  = (const float4*)w_eff;
    float qa[4][8], wa[4][8];
    #pragma unroll
    for (int j = 0; j < 4; ++j) {
        const float4 qlo = gp2[32 * j + 2 * c], qhi = gp2[32 * j + 2 * c + 1];
        const float4 wlo = gw[32 * j + 2 * c],  whi = gw[32 * j + 2 * c + 1];
        qa[j][0] = qlo.x * LOG2E2; qa[j][1] = qlo.y * LOG2E2;
        qa[j][2] = qlo.z * LOG2E2; qa[j][3] = qlo.w * LOG2E2;
        qa[j][4] = qhi.x * LOG2E2; qa[j][5] = qhi.y * LOG2E2;
        qa[j][6] = qhi.z * LOG2E2; qa[j][7] = qhi.w * LOG2E2;
        wa[j][0] = wlo.x; wa[j][1] = wlo.y; wa[j][2] = wlo.z; wa[j][3] = wlo.w;
        wa[j][4] = whi.x; wa[j][5] = whi.y; wa[j][6] = whi.z; wa[j][7] = whi.w;
    }

    const unsigned short* p1b = p1 + (size_t)b * P_ * ATT;
    const int nch = (wave == 0) ? 13 : 12;
    const int ptail = 192 + g;
    ushort8x cur[4], nxt[4];
    {
        const int row0 = 4 * wave + g;
        const ushort8x* row = (const ushort8x*)(p1b + (size_t)row0 * ATT);
        #pragma unroll
        for (int j = 0; j < 4; ++j) cur[j] = row[c + 16 * j];
    }
    for (int i = 0; i < nch; ++i) {
        const int pr = (i < 12) ? (16 * i + 4 * wave + g) : ptail;
        if (i + 1 < nch) {
            const int pn = (i + 1 < 12) ? (16 * (i + 1) + 4 * wave + g) : ptail;
            const ushort8x* row = (const ushort8x*)(p1b + (size_t)pn * ATT);
            #pragma unroll
            for (int j = 0; j < 4; ++j) nxt[j] = row[c + 16 * j];
        }
        float acc = 0.f;
        #pragma unroll
        for (int j = 0; j < 4; ++j) {
            float r[8];
            #pragma unroll
            for (int e = 0; e < 8; ++e)
                r[e] = __uint_as_float((unsigned)cur[j][e] << 16);
            #pragma unroll
            for (int pq = 0; pq < 4; ++pq) {
                const float e0 = __builtin_amdgcn_exp2f(r[2 * pq]     * qa[j][2 * pq]);
                const float e1 = __builtin_amdgcn_exp2f(r[2 * pq + 1] * qa[j][2 * pq + 1]);
                const float w0 = wa[j][2 * pq], w1 = wa[j][2 * pq + 1];
                const float num = fmaf(w0, e1, fmaf(w1, e0, w0 + w1));
                const float den = fmaf(e0, e1, e0 + e1 + 1.f);
                acc = fmaf(num, __builtin_amdgcn_rcpf(den), acc);
            }
        }
        acc += __shfl_xor(acc, 1);
        acc += __shfl_xor(acc, 2);
        acc += __shfl_xor(acc, 4);
        acc += __shfl_xor(acc, 8);
        if (c == 0) s_t[pr] = acc;
        #pragma unroll
        for (int j = 0; j < 4; ++j) cur[j] = nxt[j];
    }
    __syncthreads();
    // softmax over p of v = -2*S   (TAU = 1; bias & Wsum cancel)
    const float v = (tid < P_) ? -2.f * s_t[tid] : -1e30f;
    float m = v;
    #pragma unroll
    for (int off = 32; off >= 1; off >>= 1) m = fmaxf(m, __shfl_xor(m, off));
    if (lane == 0) s_red[wave] = m;
    __syncthreads();
    m = fmaxf(fmaxf(s_red[0], s_red[1]), fmaxf(s_red[2], s_red[3]));
    __syncthreads();
    const float e = (tid < P_) ? __expf(v - m) : 0.f;
    float s = e;
    #pragma unroll
    for (int off = 32; off >= 1; off >>= 1) s += __shfl_xor(s, off);
    if (lane == 0) s_red[wave] = s;
    __syncthreads();
    s = s_red[0] + s_red[1] + s_red[2] + s_red[3];
    if (tid < P_) alpha[(size_t)bl * P_ + tid] = e / s;
}

// ------- label_repr[b,l,d] = sum_p alpha[b,l,p] * x1[b,p,d] -------
// grid (8 dt, 5 lt, 16 b) = 640 blocks; NO LDS: alpha[l][p] is lane-invariant,
// so it is read through block-uniform indices -> s_load + SGPR-operand FMA.
__global__ __launch_bounds__(256)
void label_kernel(const float* __restrict__ alpha, const float* __restrict__ x1,
                  float* __restrict__ out) {
    const int dt = blockIdx.x;   // 0..7
    const int lt = blockIdx.y;   // 0..4
    const int b  = blockIdx.z;   // 0..15
    const int tid = threadIdx.x;
    const int d = dt * 256 + tid;
    const float* xcol = x1 + (size_t)b * P_ * DIM1 + d;
    const float* arow = alpha + (size_t)(b * L_ + lt * 16) * P_;  // block-uniform
    float acc[16] = {};
    for (int p = 0; p < P_; p += 4) {            // 196 = 4*49, no tail
        const float xv0 = xcol[(size_t)(p + 0) * DIM1];
        const float xv1 = xcol[(size_t)(p + 1) * DIM1];
        const float xv2 = xcol[(size_t)(p + 2) * DIM1];
        const float xv3 = xcol[(size_t)(p + 3) * DIM1];
        #pragma unroll
        for (int i = 0; i < 16; ++i) {
            const float* ap = arow + i * P_ + p;   // uniform -> s_load_dwordx4
            acc[i] = fmaf(ap[0], xv0,
                     fmaf(ap[1], xv1,
                     fmaf(ap[2], xv2,
                     fmaf(ap[3], xv3, acc[i]))));
        }
    }
    #pragma unroll
    for (int i = 0; i < 16; ++i)
        out[(size_t)(b * L_ + lt * 16 + i) * DIM1 + d] = acc[i];
}

extern "C" void kernel_launch(void* const* d_in, const int* in_sizes, int n_in,
                              void* d_out, int out_size, void* d_ws, size_t ws_size,
                              hipStream_t stream) {
    const float* x1 = (const float*)d_in[0];   // (B,P,DIM1)
    const float* x2 = (const float*)d_in[1];   // (B,L,DIM2)
    const float* W1 = (const float*)d_in[2];   // (ATT,DIM1)
    const float* W2 = (const float*)d_in[3];   // (ATT,DIM2)
    const float* Wh = (const float*)d_in[4];   // (ATT,ATT)
    const float* Wt = (const float*)d_in[6];   // (1,ATT)
    // bh (d_in[5]) and bt (d_in[7]) cancel in the softmax — unused.

    char* base = (char*)d_ws;
    unsigned short* p1b = (unsigned short*)base;                     // 3136*512*2  = 3,211,264 B
    float* p2    = (float*)(base + 3211264);                          // 1280*512*4  = 2,621,440 B
    float* w_eff = (float*)(base + 3211264 + 2621440);                // 2,048 B
    unsigned short* x1b = (unsigned short*)(base + 3211264 + 2621440 + 2048);  // 12,845,056 B
    unsigned short* W1b = x1b + (size_t)B_ * P_ * DIM1;               // 2,097,152 B

    float* label = (float*)d_out;                        // (B,L,DIM1)
    float* alpha = label + (size_t)B_ * L_ * DIM1;       // (B,L,P)

    hipLaunchKernelGGL(cvt_bf16_kernel, dim3(2048), dim3(256), 0, stream,
                       x1, x1b, (B_ * P_ * DIM1) / 4);
    hipLaunchKernelGGL(cvt_bf16_kernel, dim3(512), dim3(256), 0, stream,
                       W1, W1b, (ATT * DIM1) / 4);
    hipLaunchKernelGGL(weff_kernel, dim3(8), dim3(256), 0, stream, Wh, Wt, w_eff);
    hipLaunchKernelGGL(gemm_nt, dim3((B_ * L_) / 64, ATT / 64), dim3(256), 0, stream,
                       x2, W2, p2, B_ * L_, ATT, DIM2);
    hipLaunchKernelGGL(gemm_bf16_mfma, dim3(GN / 32, GM / 64), dim3(256), 0, stream,
                       x1b, W1b, p1b);
    hipLaunchKernelGGL(score_softmax_kernel, dim3(B_ * L_), dim3(256), 0, stream,
                       p1b, p2, w_eff, alpha);
    hipLaunchKernelGGL(label_kernel, dim3(8, 5, B_), dim3(256), 0, stream,
                       alpha, x1, label);
}

// Round 10
// 197.212 us; speedup vs baseline: 1.0578x; 1.0578x over previous
//
#include <hip/hip_runtime.h>

#define B_   16
#define P_   196
#define L_   80
#define DIM1 2048
#define DIM2 300
#define ATT  512

typedef __attribute__((ext_vector_type(8))) short short8x;
typedef __attribute__((ext_vector_type(8))) unsigned short ushort8x;
typedef __attribute__((ext_vector_type(4))) float f32x4;
typedef __attribute__((ext_vector_type(4))) unsigned int uint4x;
typedef __attribute__((ext_vector_type(4))) unsigned short ushort4x;

__device__ __forceinline__ unsigned short f2bf(float f) {
    unsigned v = __float_as_uint(f);
    v += 0x7fffu + ((v >> 16) & 1u);
    return (unsigned short)(v >> 16);
}

// =============== fused prep: cvt x1, cvt W1, w_eff (no GEMM tail) ===============
// blocks [0,2048): x1 -> x1b ; [2048,2560): W1 -> W1b ; [2560,2568): w_eff
__global__ __launch_bounds__(256)
void prep_kernel(const float* __restrict__ x1, const float* __restrict__ W1,
                 const float* __restrict__ Wh, const float* __restrict__ Wt,
                 unsigned short* __restrict__ x1b, unsigned short* __restrict__ W1b,
                 float* __restrict__ w_eff) {
    __shared__ float part[4][64];
    const int blk = blockIdx.x, tid = threadIdx.x;
    if (blk < 2048) {
        const int n4 = (B_ * P_ * DIM1) / 4;
        for (int i = blk * 256 + tid; i < n4; i += 2048 * 256) {
            uint4x u = ((const uint4x*)x1)[i];
            ushort4x o;
            #pragma unroll
            for (int j = 0; j < 4; ++j) {
                unsigned v = u[j];
                v += 0x7fffu + ((v >> 16) & 1u);
                o[j] = (unsigned short)(v >> 16);
            }
            ((ushort4x*)x1b)[i] = o;
        }
    } else if (blk < 2560) {
        const int n4 = (ATT * DIM1) / 4;
        for (int i = (blk - 2048) * 256 + tid; i < n4; i += 512 * 256) {
            uint4x u = ((const uint4x*)W1)[i];
            ushort4x o;
            #pragma unroll
            for (int j = 0; j < 4; ++j) {
                unsigned v = u[j];
                v += 0x7fffu + ((v >> 16) & 1u);
                o[j] = (unsigned short)(v >> 16);
            }
            ((ushort4x*)W1b)[i] = o;
        }
    } else {
        const int bix = blk - 2560;
        const int lane = tid & 63, quad = tid >> 6;
        const int a = bix * 64 + lane;
        float s = 0.f;
        const int c0 = quad * 128;
        for (int c = c0; c < c0 + 128; ++c)
            s = fmaf(Wt[c], Wh[(size_t)c * ATT + a], s);
        part[quad][lane] = s;
        __syncthreads();
        if (tid < 64)
            w_eff[bix * 64 + tid] =
                (part[0][tid] + part[1][tid]) + (part[2][tid] + part[3][tid]);
    }
}

// ---------- generic tiled NT GEMM (fp32): p2 = x2 * W2^T ----------
__global__ __launch_bounds__(256)
void gemm_nt(const float* __restrict__ A, const float* __restrict__ Bm,
             float* __restrict__ C, int M, int N, int K) {
    constexpr int BK = 16;
    __shared__ float As[BK][64];
    __shared__ float Bs[BK][64];
    const int tid  = threadIdx.x;
    const int bm   = blockIdx.x * 64;
    const int bn   = blockIdx.y * 64;
    const int ty   = tid >> 4;
    const int tx   = tid & 15;
    const int lrow = tid >> 2;
    const int lc4  = (tid & 3) << 2;
    float acc[4][4] = {};
    const float* Arow = A  + (size_t)(bm + lrow) * K;
    const float* Brow = Bm + (size_t)(bn + lrow) * K;

    for (int k0 = 0; k0 < K; k0 += BK) {
        float4 av, bv;
        if (k0 + BK <= K) {
            av = *(const float4*)(Arow + k0 + lc4);
            bv = *(const float4*)(Brow + k0 + lc4);
        } else {
            float a_[4], b_[4];
            #pragma unroll
            for (int i = 0; i < 4; ++i) {
                const int k = k0 + lc4 + i;
                a_[i] = (k < K) ? Arow[k] : 0.f;
                b_[i] = (k < K) ? Brow[k] : 0.f;
            }
            av = make_float4(a_[0], a_[1], a_[2], a_[3]);
            bv = make_float4(b_[0], b_[1], b_[2], b_[3]);
        }
        __syncthreads();
        As[lc4 + 0][lrow] = av.x;  As[lc4 + 1][lrow] = av.y;
        As[lc4 + 2][lrow] = av.z;  As[lc4 + 3][lrow] = av.w;
        Bs[lc4 + 0][lrow] = bv.x;  Bs[lc4 + 1][lrow] = bv.y;
        Bs[lc4 + 2][lrow] = bv.z;  Bs[lc4 + 3][lrow] = bv.w;
        __syncthreads();
        #pragma unroll
        for (int k = 0; k < BK; ++k) {
            const float4 a4 = *(const float4*)&As[k][ty << 2];
            const float4 b4 = *(const float4*)&Bs[k][tx << 2];
            const float ae[4] = {a4.x, a4.y, a4.z, a4.w};
            const float be[4] = {b4.x, b4.y, b4.z, b4.w};
            #pragma unroll
            for (int i = 0; i < 4; ++i)
                #pragma unroll
                for (int j = 0; j < 4; ++j)
                    acc[i][j] = fmaf(ae[i], be[j], acc[i][j]);
        }
    }
    #pragma unroll
    for (int i = 0; i < 4; ++i) {
        float4 o = make_float4(acc[i][0], acc[i][1], acc[i][2], acc[i][3]);
        *(float4*)(C + (size_t)(bm + (ty << 2) + i) * N + bn + (tx << 2)) = o;
    }
}

// ---------------- bf16 MFMA GEMM: p1b[M,N] (bf16) = x1b * W1b^T ----------------
#define GM 3136
#define GN 512
#define GK 2048

__device__ __forceinline__ void gload16(const unsigned short* g, unsigned short* l) {
    __builtin_amdgcn_global_load_lds(
        (const __attribute__((address_space(1))) unsigned int*)g,
        (__attribute__((address_space(3))) unsigned int*)l, 16, 0, 0);
}

__global__ __launch_bounds__(256)
void gemm_bf16_mfma(const unsigned short* __restrict__ Ab,
                    const unsigned short* __restrict__ Bb,
                    unsigned short* __restrict__ C) {
    __shared__ unsigned short As[2][64 * 64];
    __shared__ unsigned short Bs[2][32 * 64];
    const int tid  = threadIdx.x;
    const int wid  = tid >> 6;
    const int lane = tid & 63;
    const int bm   = blockIdx.y * 64;
    const int bn   = blockIdx.x * 32;

    const int srow = lane >> 3;                       // 0..7
    const int scol = ((lane & 7) ^ srow) << 3;        // pre-swizzled source col
    const size_t arow0 = (size_t)(bm + (wid << 4) + srow) * GK;
    const size_t brow0 = (size_t)(bn + (wid << 3) + srow) * GK;

#define STAGE_TILE(buf, k0)                                                              \
    {                                                                                    \
        gload16(Ab + arow0 + (k0) + scol,                  &As[buf][((wid << 4) + 0) * 64]); \
        gload16(Ab + arow0 + (size_t)8 * GK + (k0) + scol, &As[buf][((wid << 4) + 8) * 64]); \
        gload16(Bb + brow0 + (k0) + scol,                  &Bs[buf][(wid << 3) * 64]);       \
    }

    f32x4 acc[2] = {};
    const int fr  = lane & 15;
    const int kb  = (lane >> 4) << 3;
    const int swz = (lane & 7) << 4;

    STAGE_TILE(0, 0)
    constexpr int NT = GK / 64;
    for (int kt = 0; kt < NT; ++kt) {
        __syncthreads();
        if (kt + 1 < NT) STAGE_TILE((kt + 1) & 1, (kt + 1) * 64)
        const char* pa = (const char*)&As[kt & 1][0];
        const char* pb = (const char*)&Bs[kt & 1][0];
        #pragma unroll
        for (int kk = 0; kk < 2; ++kk) {
            const int koff = ((kk * 32 + kb) * 2) ^ swz;
            short8x a = *(const short8x*)(pa + ((wid << 4) + fr) * 128 + koff);
            short8x b[2];
            #pragma unroll
            for (int n = 0; n < 2; ++n)
                b[n] = *(const short8x*)(pb + (n * 16 + fr) * 128 + koff);
            #pragma unroll
            for (int n = 0; n < 2; ++n)
                acc[n] = __builtin_amdgcn_mfma_f32_16x16x32_bf16(a, b[n], acc[n], 0, 0, 0);
        }
        __syncthreads();
    }

    const int crow = (lane >> 4) << 2;
    #pragma unroll
    for (int n = 0; n < 2; ++n)
        #pragma unroll
        for (int j = 0; j < 4; ++j)
            C[(size_t)(bm + (wid << 4) + crow + j) * GN + bn + n * 16 + fr] =
                f2bf(acc[n][j]);
#undef STAGE_TILE
}

// ------- fused score + softmax: one block per (b,l); writes alpha -------
#define LOG2E2 2.8853900817779268f   // 2*log2(e)

__global__ __launch_bounds__(256)
void score_softmax_kernel(const unsigned short* __restrict__ p1,
                          const float* __restrict__ p2,
                          const float* __restrict__ w_eff,
                          float* __restrict__ alpha) {
    const int bidx = blockIdx.x;
    const int bl = (bidx & 7) * 160 + (bidx >> 3);
    const int b  = bl / L_;
    __shared__ float s_t[P_];
    __shared__ float s_red[4];
    const int tid = threadIdx.x, wave = tid >> 6, lane = tid & 63;
    const int g = lane >> 4, c = lane & 15;

    const float4* gp2 = (const float4*)(p2 + (size_t)bl * ATT);
    const float4* gw  = (const float4*)w_eff;
    float qa[4][8], wa[4][8];
    #pragma unroll
    for (int j = 0; j < 4; ++j) {
        const float4 qlo = gp2[32 * j + 2 * c], qhi = gp2[32 * j + 2 * c + 1];
        const float4 wlo = gw[32 * j + 2 * c],  whi = gw[32 * j + 2 * c + 1];
        qa[j][0] = qlo.x * LOG2E2; qa[j][1] = qlo.y * LOG2E2;
        qa[j][2] = qlo.z * LOG2E2; qa[j][3] = qlo.w * LOG2E2;
        qa[j][4] = qhi.x * LOG2E2; qa[j][5] = qhi.y * LOG2E2;
        qa[j][6] = qhi.z * LOG2E2; qa[j][7] = qhi.w * LOG2E2;
        wa[j][0] = wlo.x; wa[j][1] = wlo.y; wa[j][2] = wlo.z; wa[j][3] = wlo.w;
        wa[j][4] = whi.x; wa[j][5] = whi.y; wa[j][6] = whi.z; wa[j][7] = whi.w;
    }

    const unsigned short* p1b = p1 + (size_t)b * P_ * ATT;
    const int nch = (wave == 0) ? 13 : 12;
    const int ptail = 192 + g;
    ushort8x cur[4], nxt[4];
    {
        const int row0 = 4 * wave + g;
        const ushort8x* row = (const ushort8x*)(p1b + (size_t)row0 * ATT);
        #pragma unroll
        for (int j = 0; j < 4; ++j) cur[j] = row[c + 16 * j];
    }
    for (int i = 0; i < nch; ++i) {
        const int pr = (i < 12) ? (16 * i + 4 * wave + g) : ptail;
        if (i + 1 < nch) {
            const int pn = (i + 1 < 12) ? (16 * (i + 1) + 4 * wave + g) : ptail;
            const ushort8x* row = (const ushort8x*)(p1b + (size_t)pn * ATT);
            #pragma unroll
            for (int j = 0; j < 4; ++j) nxt[j] = row[c + 16 * j];
        }
        float acc = 0.f;
        #pragma unroll
        for (int j = 0; j < 4; ++j) {
            float r[8];
            #pragma unroll
            for (int e = 0; e < 8; ++e)
                r[e] = __uint_as_float((unsigned)cur[j][e] << 16);
            #pragma unroll
            for (int pq = 0; pq < 4; ++pq) {
                const float e0 = __builtin_amdgcn_exp2f(r[2 * pq]     * qa[j][2 * pq]);
                const float e1 = __builtin_amdgcn_exp2f(r[2 * pq + 1] * qa[j][2 * pq + 1]);
                const float w0 = wa[j][2 * pq], w1 = wa[j][2 * pq + 1];
                const float num = fmaf(w0, e1, fmaf(w1, e0, w0 + w1));
                const float den = fmaf(e0, e1, e0 + e1 + 1.f);
                acc = fmaf(num, __builtin_amdgcn_rcpf(den), acc);
            }
        }
        acc += __shfl_xor(acc, 1);
        acc += __shfl_xor(acc, 2);
        acc += __shfl_xor(acc, 4);
        acc += __shfl_xor(acc, 8);
        if (c == 0) s_t[pr] = acc;
        #pragma unroll
        for (int j = 0; j < 4; ++j) cur[j] = nxt[j];
    }
    __syncthreads();
    const float v = (tid < P_) ? -2.f * s_t[tid] : -1e30f;
    float m = v;
    #pragma unroll
    for (int off = 32; off >= 1; off >>= 1) m = fmaxf(m, __shfl_xor(m, off));
    if (lane == 0) s_red[wave] = m;
    __syncthreads();
    m = fmaxf(fmaxf(s_red[0], s_red[1]), fmaxf(s_red[2], s_red[3]));
    __syncthreads();
    const float e = (tid < P_) ? __expf(v - m) : 0.f;
    float s = e;
    #pragma unroll
    for (int off = 32; off >= 1; off >>= 1) s += __shfl_xor(s, off);
    if (lane == 0) s_red[wave] = s;
    __syncthreads();
    s = s_red[0] + s_red[1] + s_red[2] + s_red[3];
    if (tid < P_) alpha[(size_t)bl * P_ + tid] = e / s;
}

// ------- label_repr[b,l,d] = sum_p alpha[b,l,p] * x1b[b,p,d] (bf16 x1) -------
// 640 blocks, XCD-chunked decode: dt = raw&7 -> all blocks of one d-slice on
// one XCD (x1b slice 1.6MB L2-resident, lt re-reads hit L2).
// Thread = 4l x 4d: per p, 1 uniform b128 alpha + 1 ushort4 x1b + 16 FMA.
__global__ __launch_bounds__(256)
void label_kernel(const float* __restrict__ alpha, const unsigned short* __restrict__ x1b,
                  float* __restrict__ out) {
    const int raw = blockIdx.x;
    const int dt = raw & 7;        // XCD id
    const int t  = raw >> 3;
    const int lt = t % 5;
    const int b  = t / 5;
    __shared__ float s_alpha[P_][16];
    const int tid = threadIdx.x;
    for (int idx = tid; idx < 16 * P_; idx += 256) {
        const int p = idx >> 4, i = idx & 15;
        s_alpha[p][i] = alpha[(size_t)(b * L_ + lt * 16 + i) * P_ + p];
    }
    __syncthreads();
    const int ty = tid >> 6, tx = tid & 63;   // wave = ty (uniform l-quad)
    const int d  = dt * 256 + tx * 4;
    const unsigned short* xp = x1b + (size_t)b * P_ * DIM1 + d;
    f32x4 acc[4] = {};
    for (int p = 0; p < P_; p += 4) {         // 196 = 4*49, exact
        #pragma unroll
        for (int u = 0; u < 4; ++u) {
            const ushort4x xv = *(const ushort4x*)(xp + (size_t)(p + u) * DIM1);
            float xf[4];
            #pragma unroll
            for (int j = 0; j < 4; ++j)
                xf[j] = __uint_as_float((unsigned)xv[j] << 16);
            const float4 a = *(const float4*)&s_alpha[p + u][ty << 2];
            const float av[4] = {a.x, a.y, a.z, a.w};
            #pragma unroll
            for (int i2 = 0; i2 < 4; ++i2)
                #pragma unroll
                for (int j = 0; j < 4; ++j)
                    acc[i2][j] = fmaf(av[i2], xf[j], acc[i2][j]);
        }
    }
    const int lbase = b * L_ + lt * 16 + (ty << 2);
    #pragma unroll
    for (int i2 = 0; i2 < 4; ++i2)
        *(f32x4*)(out + (size_t)(lbase + i2) * DIM1 + d) = acc[i2];
}

extern "C" void kernel_launch(void* const* d_in, const int* in_sizes, int n_in,
                              void* d_out, int out_size, void* d_ws, size_t ws_size,
                              hipStream_t stream) {
    const float* x1 = (const float*)d_in[0];   // (B,P,DIM1)
    const float* x2 = (const float*)d_in[1];   // (B,L,DIM2)
    const float* W1 = (const float*)d_in[2];   // (ATT,DIM1)
    const float* W2 = (const float*)d_in[3];   // (ATT,DIM2)
    const float* Wh = (const float*)d_in[4];   // (ATT,ATT)
    const float* Wt = (const float*)d_in[6];   // (1,ATT)
    // bh (d_in[5]) and bt (d_in[7]) cancel in the softmax — unused.

    char* base = (char*)d_ws;
    unsigned short* p1b = (unsigned short*)base;                     // 3,211,264 B
    float* p2    = (float*)(base + 3211264);                          // 2,621,440 B
    float* w_eff = (float*)(base + 3211264 + 2621440);                // 2,048 B
    unsigned short* x1b = (unsigned short*)(base + 3211264 + 2621440 + 2048);  // 12,845,056 B
    unsigned short* W1b = x1b + (size_t)B_ * P_ * DIM1;               // 2,097,152 B

    float* label = (float*)d_out;                        // (B,L,DIM1)
    float* alpha = label + (size_t)B_ * L_ * DIM1;       // (B,L,P)

    hipLaunchKernelGGL(prep_kernel, dim3(2568), dim3(256), 0, stream,
                       x1, W1, Wh, Wt, x1b, W1b, w_eff);
    hipLaunchKernelGGL(gemm_nt, dim3((B_ * L_) / 64, ATT / 64), dim3(256), 0, stream,
                       x2, W2, p2, B_ * L_, ATT, DIM2);
    hipLaunchKernelGGL(gemm_bf16_mfma, dim3(GN / 32, GM / 64), dim3(256), 0, stream,
                       x1b, W1b, p1b);
    hipLaunchKernelGGL(score_softmax_kernel, dim3(B_ * L_), dim3(256), 0, stream,
                       p1b, p2, w_eff, alpha);
    hipLaunchKernelGGL(label_kernel, dim3(640), dim3(256), 0, stream,
                       alpha, x1b, label);
}

// Round 11
// 187.509 us; speedup vs baseline: 1.1125x; 1.0517x over previous
//
#include <hip/hip_runtime.h>

#define B_   16
#define P_   196
#define L_   80
#define DIM1 2048
#define DIM2 300
#define ATT  512

typedef __attribute__((ext_vector_type(8))) short short8x;
typedef __attribute__((ext_vector_type(8))) unsigned short ushort8x;
typedef __attribute__((ext_vector_type(4))) float f32x4;
typedef __attribute__((ext_vector_type(4))) unsigned int uint4x;
typedef __attribute__((ext_vector_type(4))) unsigned short ushort4x;

__device__ __forceinline__ unsigned short f2bf(float f) {
    unsigned v = __float_as_uint(f);
    v += 0x7fffu + ((v >> 16) & 1u);
    return (unsigned short)(v >> 16);
}

// ========== fused prep: p2 GEMM (head) + cvt x1 + cvt W1 + w_eff ==========
// blocks [0,160): p2 = x2*W2^T (fp32 NT GEMM, M=1280,N=512,K=300) -- head so
//                 the long-pole GEMM starts immediately, cvt streams behind.
// blocks [160,2208): x1 -> x1b ; [2208,2720): W1 -> W1b ; [2720,2728): w_eff
__global__ __launch_bounds__(256)
void prep_kernel(const float* __restrict__ x1, const float* __restrict__ W1,
                 const float* __restrict__ Wh, const float* __restrict__ Wt,
                 const float* __restrict__ x2, const float* __restrict__ W2,
                 unsigned short* __restrict__ x1b, unsigned short* __restrict__ W1b,
                 float* __restrict__ w_eff, float* __restrict__ p2) {
    __shared__ float As[16][64];
    __shared__ float Bs[16][64];
    __shared__ float part[4][64];
    const int blk = blockIdx.x, tid = threadIdx.x;

    if (blk < 160) {                        // ---- p2 GEMM ----
        const int bm = (blk % 20) * 64;
        const int bn = (blk / 20) * 64;
        const int N = ATT, K = DIM2;
        const int ty = tid >> 4, tx = tid & 15;
        const int lrow = tid >> 2, lc4 = (tid & 3) << 2;
        float acc[4][4] = {};
        const float* Arow = x2 + (size_t)(bm + lrow) * K;
        const float* Brow = W2 + (size_t)(bn + lrow) * K;
        for (int k0 = 0; k0 < K; k0 += 16) {
            float4 av, bv;
            if (k0 + 16 <= K) {
                av = *(const float4*)(Arow + k0 + lc4);
                bv = *(const float4*)(Brow + k0 + lc4);
            } else {
                float a_[4], b_[4];
                #pragma unroll
                for (int i = 0; i < 4; ++i) {
                    const int k = k0 + lc4 + i;
                    a_[i] = (k < K) ? Arow[k] : 0.f;
                    b_[i] = (k < K) ? Brow[k] : 0.f;
                }
                av = make_float4(a_[0], a_[1], a_[2], a_[3]);
                bv = make_float4(b_[0], b_[1], b_[2], b_[3]);
            }
            __syncthreads();
            As[lc4 + 0][lrow] = av.x;  As[lc4 + 1][lrow] = av.y;
            As[lc4 + 2][lrow] = av.z;  As[lc4 + 3][lrow] = av.w;
            Bs[lc4 + 0][lrow] = bv.x;  Bs[lc4 + 1][lrow] = bv.y;
            Bs[lc4 + 2][lrow] = bv.z;  Bs[lc4 + 3][lrow] = bv.w;
            __syncthreads();
            #pragma unroll
            for (int k = 0; k < 16; ++k) {
                const float4 a4 = *(const float4*)&As[k][ty << 2];
                const float4 b4 = *(const float4*)&Bs[k][tx << 2];
                const float ae[4] = {a4.x, a4.y, a4.z, a4.w};
                const float be[4] = {b4.x, b4.y, b4.z, b4.w};
                #pragma unroll
                for (int i = 0; i < 4; ++i)
                    #pragma unroll
                    for (int j = 0; j < 4; ++j)
                        acc[i][j] = fmaf(ae[i], be[j], acc[i][j]);
            }
        }
        #pragma unroll
        for (int i = 0; i < 4; ++i) {
            float4 o = make_float4(acc[i][0], acc[i][1], acc[i][2], acc[i][3]);
            *(float4*)(p2 + (size_t)(bm + (ty << 2) + i) * N + bn + (tx << 2)) = o;
        }
    } else if (blk < 2208) {                // ---- cvt x1 ----
        const int n4 = (B_ * P_ * DIM1) / 4;
        for (int i = (blk - 160) * 256 + tid; i < n4; i += 2048 * 256) {
            uint4x u = ((const uint4x*)x1)[i];
            ushort4x o;
            #pragma unroll
            for (int j = 0; j < 4; ++j) {
                unsigned v = u[j];
                v += 0x7fffu + ((v >> 16) & 1u);
                o[j] = (unsigned short)(v >> 16);
            }
            ((ushort4x*)x1b)[i] = o;
        }
    } else if (blk < 2720) {                // ---- cvt W1 ----
        const int n4 = (ATT * DIM1) / 4;
        for (int i = (blk - 2208) * 256 + tid; i < n4; i += 512 * 256) {
            uint4x u = ((const uint4x*)W1)[i];
            ushort4x o;
            #pragma unroll
            for (int j = 0; j < 4; ++j) {
                unsigned v = u[j];
                v += 0x7fffu + ((v >> 16) & 1u);
                o[j] = (unsigned short)(v >> 16);
            }
            ((ushort4x*)W1b)[i] = o;
        }
    } else {                                // ---- w_eff ----
        const int bix = blk - 2720;
        const int lane = tid & 63, quad = tid >> 6;
        const int a = bix * 64 + lane;
        float s = 0.f;
        const int c0 = quad * 128;
        for (int c = c0; c < c0 + 128; ++c)
            s = fmaf(Wt[c], Wh[(size_t)c * ATT + a], s);
        part[quad][lane] = s;
        __syncthreads();
        if (tid < 64)
            w_eff[bix * 64 + tid] =
                (part[0][tid] + part[1][tid]) + (part[2][tid] + part[3][tid]);
    }
}

// ---------------- bf16 MFMA GEMM: p1b (bf16) = x1b * W1b^T ----------------
// 64x64 tile (BK=64), 4 waves as 2x2 of 32x32 quadrants (8 MFMA : 8 ds_b128
// per wave per K-step). grid (8 bn, 49 bm). Both-sides XOR swizzle.
#define GM 3136
#define GN 512
#define GK 2048

__device__ __forceinline__ void gload16(const unsigned short* g, unsigned short* l) {
    __builtin_amdgcn_global_load_lds(
        (const __attribute__((address_space(1))) unsigned int*)g,
        (__attribute__((address_space(3))) unsigned int*)l, 16, 0, 0);
}

__global__ __launch_bounds__(256)
void gemm_bf16_mfma(const unsigned short* __restrict__ Ab,
                    const unsigned short* __restrict__ Bb,
                    unsigned short* __restrict__ C) {
    __shared__ unsigned short As[2][64 * 64];
    __shared__ unsigned short Bs[2][64 * 64];
    const int tid  = threadIdx.x;
    const int wid  = tid >> 6;
    const int lane = tid & 63;
    const int bm   = blockIdx.y * 64;
    const int bn   = blockIdx.x * 64;
    const int wm   = wid >> 1;          // 0,1
    const int wn   = wid & 1;           // 0,1

    const int srow = lane >> 3;                       // 0..7
    const int scol = ((lane & 7) ^ srow) << 3;        // pre-swizzled source col
    const size_t arow0 = (size_t)(bm + (wid << 4) + srow) * GK;
    const size_t brow0 = (size_t)(bn + (wid << 4) + srow) * GK;

#define STAGE_TILE(buf, k0)                                                        \
    {                                                                              \
        gload16(Ab + arow0 + (k0) + scol,            &As[buf][((wid << 4) + 0) * 64]); \
        gload16(Ab + arow0 + (size_t)8 * GK + (k0) + scol, &As[buf][((wid << 4) + 8) * 64]); \
        gload16(Bb + brow0 + (k0) + scol,            &Bs[buf][((wid << 4) + 0) * 64]); \
        gload16(Bb + brow0 + (size_t)8 * GK + (k0) + scol, &Bs[buf][((wid << 4) + 8) * 64]); \
    }

    f32x4 acc[2][2] = {};
    const int fr  = lane & 15;
    const int kb  = (lane >> 4) << 3;
    const int swz = (lane & 7) << 4;

    STAGE_TILE(0, 0)
    constexpr int NT = GK / 64;
    for (int kt = 0; kt < NT; ++kt) {
        __syncthreads();
        if (kt + 1 < NT) STAGE_TILE((kt + 1) & 1, (kt + 1) * 64)
        const char* pa = (const char*)&As[kt & 1][0];
        const char* pb = (const char*)&Bs[kt & 1][0];
        #pragma unroll
        for (int kk = 0; kk < 2; ++kk) {
            const int koff = ((kk * 32 + kb) * 2) ^ swz;
            short8x a[2], b[2];
            #pragma unroll
            for (int m = 0; m < 2; ++m)
                a[m] = *(const short8x*)(pa + (wm * 32 + m * 16 + fr) * 128 + koff);
            #pragma unroll
            for (int n = 0; n < 2; ++n)
                b[n] = *(const short8x*)(pb + (wn * 32 + n * 16 + fr) * 128 + koff);
            #pragma unroll
            for (int m = 0; m < 2; ++m)
                #pragma unroll
                for (int n = 0; n < 2; ++n)
                    acc[m][n] = __builtin_amdgcn_mfma_f32_16x16x32_bf16(a[m], b[n], acc[m][n], 0, 0, 0);
        }
        __syncthreads();
    }

    const int crow = (lane >> 4) << 2;
    #pragma unroll
    for (int m = 0; m < 2; ++m)
        #pragma unroll
        for (int n = 0; n < 2; ++n)
            #pragma unroll
            for (int j = 0; j < 4; ++j)
                C[(size_t)(bm + wm * 32 + m * 16 + crow + j) * GN + bn + wn * 32 + n * 16 + fr] =
                    f2bf(acc[m][n][j]);
#undef STAGE_TILE
}

// ------- fused score + softmax: one block per (b,l); writes alpha -------
// p1 bf16; pair-rcp with hoisted w0+w1; NO max-pass: |v| = 2|sum w*sigma|
// <= 2*sum|w| ~ 12, exp2 safe in fp32.
#define LOG2E2 2.8853900817779268f   // 2*log2(e)

__global__ __launch_bounds__(256)
void score_softmax_kernel(const unsigned short* __restrict__ p1,
                          const float* __restrict__ p2,
                          const float* __restrict__ w_eff,
                          float* __restrict__ alpha) {
    const int bidx = blockIdx.x;
    const int bl = (bidx & 7) * 160 + (bidx >> 3);
    const int b  = bl / L_;
    __shared__ float s_t[P_];
    __shared__ float s_red[4];
    const int tid = threadIdx.x, wave = tid >> 6, lane = tid & 63;
    const int g = lane >> 4, c = lane & 15;

    const float4* gp2 = (const float4*)(p2 + (size_t)bl * ATT);
    const float4* gw  = (const float4*)w_eff;
    float qa[4][8], wa[4][8], ws[4][4];
    #pragma unroll
    for (int j = 0; j < 4; ++j) {
        const float4 qlo = gp2[32 * j + 2 * c], qhi = gp2[32 * j + 2 * c + 1];
        const float4 wlo = gw[32 * j + 2 * c],  whi = gw[32 * j + 2 * c + 1];
        qa[j][0] = qlo.x * LOG2E2; qa[j][1] = qlo.y * LOG2E2;
        qa[j][2] = qlo.z * LOG2E2; qa[j][3] = qlo.w * LOG2E2;
        qa[j][4] = qhi.x * LOG2E2; qa[j][5] = qhi.y * LOG2E2;
        qa[j][6] = qhi.z * LOG2E2; qa[j][7] = qhi.w * LOG2E2;
        wa[j][0] = wlo.x; wa[j][1] = wlo.y; wa[j][2] = wlo.z; wa[j][3] = wlo.w;
        wa[j][4] = whi.x; wa[j][5] = whi.y; wa[j][6] = whi.z; wa[j][7] = whi.w;
        ws[j][0] = wlo.x + wlo.y; ws[j][1] = wlo.z + wlo.w;
        ws[j][2] = whi.x + whi.y; ws[j][3] = whi.z + whi.w;
    }

    const unsigned short* p1b = p1 + (size_t)b * P_ * ATT;
    const int nch = (wave == 0) ? 13 : 12;
    const int ptail = 192 + g;
    ushort8x cur[4], nxt[4];
    {
        const int row0 = 4 * wave + g;
        const ushort8x* row = (const ushort8x*)(p1b + (size_t)row0 * ATT);
        #pragma unroll
        for (int j = 0; j < 4; ++j) cur[j] = row[c + 16 * j];
    }
    for (int i = 0; i < nch; ++i) {
        const int pr = (i < 12) ? (16 * i + 4 * wave + g) : ptail;
        if (i + 1 < nch) {
            const int pn = (i + 1 < 12) ? (16 * (i + 1) + 4 * wave + g) : ptail;
            const ushort8x* row = (const ushort8x*)(p1b + (size_t)pn * ATT);
            #pragma unroll
            for (int j = 0; j < 4; ++j) nxt[j] = row[c + 16 * j];
        }
        float acc = 0.f;
        #pragma unroll
        for (int j = 0; j < 4; ++j) {
            float r[8];
            #pragma unroll
            for (int e = 0; e < 8; ++e)
                r[e] = __uint_as_float((unsigned)cur[j][e] << 16);
            #pragma unroll
            for (int pq = 0; pq < 4; ++pq) {
                const float e0 = __builtin_amdgcn_exp2f(r[2 * pq]     * qa[j][2 * pq]);
                const float e1 = __builtin_amdgcn_exp2f(r[2 * pq + 1] * qa[j][2 * pq + 1]);
                const float num = fmaf(wa[j][2 * pq], e1,
                                  fmaf(wa[j][2 * pq + 1], e0, ws[j][pq]));
                const float den = fmaf(e0, e1, e0 + e1 + 1.f);
                acc = fmaf(num, __builtin_amdgcn_rcpf(den), acc);
            }
        }
        acc += __shfl_xor(acc, 1);
        acc += __shfl_xor(acc, 2);
        acc += __shfl_xor(acc, 4);
        acc += __shfl_xor(acc, 8);
        if (c == 0) s_t[pr] = acc;
        #pragma unroll
        for (int j = 0; j < 4; ++j) cur[j] = nxt[j];
    }
    __syncthreads();
    // softmax without max-subtraction (scores bounded, fp32-safe)
    const float e = (tid < P_) ? __builtin_amdgcn_exp2f(-LOG2E2 * s_t[tid]) : 0.f;
    float s = e;
    #pragma unroll
    for (int off = 32; off >= 1; off >>= 1) s += __shfl_xor(s, off);
    if (lane == 0) s_red[wave] = s;
    __syncthreads();
    s = s_red[0] + s_red[1] + s_red[2] + s_red[3];
    if (tid < P_) alpha[(size_t)bl * P_ + tid] = e / s;
}

// ------- label_repr[b,l,d] = sum_p alpha[b,l,p] * x1b[b,p,d] (bf16 x1) -------
__global__ __launch_bounds__(256)
void label_kernel(const float* __restrict__ alpha, const unsigned short* __restrict__ x1b,
                  float* __restrict__ out) {
    const int raw = blockIdx.x;
    const int dt = raw & 7;        // XCD id
    const int t  = raw >> 3;
    const int lt = t % 5;
    const int b  = t / 5;
    __shared__ float s_alpha[P_][16];
    const int tid = threadIdx.x;
    for (int idx = tid; idx < 16 * P_; idx += 256) {
        const int p = idx >> 4, i = idx & 15;
        s_alpha[p][i] = alpha[(size_t)(b * L_ + lt * 16 + i) * P_ + p];
    }
    __syncthreads();
    const int ty = tid >> 6, tx = tid & 63;
    const int d  = dt * 256 + tx * 4;
    const unsigned short* xp = x1b + (size_t)b * P_ * DIM1 + d;
    f32x4 acc[4] = {};
    for (int p = 0; p < P_; p += 4) {
        #pragma unroll
        for (int u = 0; u < 4; ++u) {
            const ushort4x xv = *(const ushort4x*)(xp + (size_t)(p + u) * DIM1);
            float xf[4];
            #pragma unroll
            for (int j = 0; j < 4; ++j)
                xf[j] = __uint_as_float((unsigned)xv[j] << 16);
            const float4 a = *(const float4*)&s_alpha[p + u][ty << 2];
            const float av[4] = {a.x, a.y, a.z, a.w};
            #pragma unroll
            for (int i2 = 0; i2 < 4; ++i2)
                #pragma unroll
                for (int j = 0; j < 4; ++j)
                    acc[i2][j] = fmaf(av[i2], xf[j], acc[i2][j]);
        }
    }
    const int lbase = b * L_ + lt * 16 + (ty << 2);
    #pragma unroll
    for (int i2 = 0; i2 < 4; ++i2)
        *(f32x4*)(out + (size_t)(lbase + i2) * DIM1 + d) = acc[i2];
}

extern "C" void kernel_launch(void* const* d_in, const int* in_sizes, int n_in,
                              void* d_out, int out_size, void* d_ws, size_t ws_size,
                              hipStream_t stream) {
    const float* x1 = (const float*)d_in[0];   // (B,P,DIM1)
    const float* x2 = (const float*)d_in[1];   // (B,L,DIM2)
    const float* W1 = (const float*)d_in[2];   // (ATT,DIM1)
    const float* W2 = (const float*)d_in[3];   // (ATT,DIM2)
    const float* Wh = (const float*)d_in[4];   // (ATT,ATT)
    const float* Wt = (const float*)d_in[6];   // (1,ATT)
    // bh (d_in[5]) and bt (d_in[7]) cancel in the softmax — unused.

    char* base = (char*)d_ws;
    unsigned short* p1b = (unsigned short*)base;                     // 3,211,264 B
    float* p2    = (float*)(base + 3211264);                          // 2,621,440 B
    float* w_eff = (float*)(base + 3211264 + 2621440);                // 2,048 B
    unsigned short* x1b = (unsigned short*)(base + 3211264 + 2621440 + 2048);  // 12,845,056 B
    unsigned short* W1b = x1b + (size_t)B_ * P_ * DIM1;               // 2,097,152 B

    float* label = (float*)d_out;                        // (B,L,DIM1)
    float* alpha = label + (size_t)B_ * L_ * DIM1;       // (B,L,P)

    hipLaunchKernelGGL(prep_kernel, dim3(2728), dim3(256), 0, stream,
                       x1, W1, Wh, Wt, x2, W2, x1b, W1b, w_eff, p2);
    hipLaunchKernelGGL(gemm_bf16_mfma, dim3(GN / 64, GM / 64), dim3(256), 0, stream,
                       x1b, W1b, p1b);
    hipLaunchKernelGGL(score_softmax_kernel, dim3(B_ * L_), dim3(256), 0, stream,
                       p1b, p2, w_eff, alpha);
    hipLaunchKernelGGL(label_kernel, dim3(640), dim3(256), 0, stream,
                       alpha, x1b, label);
}